// Round 1
// baseline (154.723 us; speedup 1.0000x reference)
//
#include <hip/hip_runtime.h>

#define NN 1024
#define MM 1024
#define DD 256

__device__ __forceinline__ float rcp_fast(float x) { return __builtin_amdgcn_rcpf(x); }

// ---------------- Kernel 1: fused dual GEMM + exp epilogue ----------------
// q = f_r @ W_w^T + W_b        -> Eq[n][d]  = exp(2*q)
// k = f_rp @ Wp_w^T + Wp_b     -> EkT[d][m] = exp(2*k)   (stored transposed)
__global__ __launch_bounds__(256) void gemm_exp_kernel(
    const float* __restrict__ f_r,  const float* __restrict__ W_w,  const float* __restrict__ W_b,
    const float* __restrict__ f_rp, const float* __restrict__ Wp_w, const float* __restrict__ Wp_b,
    float* __restrict__ Eq, float* __restrict__ EkT)
{
    const int b    = blockIdx.x;
    const int mat  = b >> 6;        // 0: q-path, 1: k-path
    const int tile = b & 63;
    const int rt = tile & 15, dt = tile >> 4;     // 16 r-tiles x 4 d-tiles
    const float* __restrict__ A    = mat ? f_rp : f_r;
    const float* __restrict__ B    = mat ? Wp_w : W_w;
    const float* __restrict__ bias = mat ? Wp_b : W_b;

    __shared__ float As[16][68];   // [k][r], +4 pad keeps float4 alignment & kills conflicts
    __shared__ float Bs[16][68];   // [k][d]

    const int t  = threadIdx.x;
    const int tx = t & 15, ty = t >> 4;
    const int r0 = rt * 64, d0 = dt * 64;
    const int lr = t >> 2, lq = t & 3;

    float acc[4][4];
    #pragma unroll
    for (int i = 0; i < 4; ++i)
        #pragma unroll
        for (int j = 0; j < 4; ++j) acc[i][j] = 0.f;

    for (int kk = 0; kk < DD; kk += 16) {
        float4 av = *(const float4*)(A + (r0 + lr) * DD + kk + lq * 4);
        float4 bv = *(const float4*)(B + (d0 + lr) * DD + kk + lq * 4);
        __syncthreads();
        As[lq*4+0][lr] = av.x; As[lq*4+1][lr] = av.y; As[lq*4+2][lr] = av.z; As[lq*4+3][lr] = av.w;
        Bs[lq*4+0][lr] = bv.x; Bs[lq*4+1][lr] = bv.y; Bs[lq*4+2][lr] = bv.z; Bs[lq*4+3][lr] = bv.w;
        __syncthreads();
        #pragma unroll
        for (int k = 0; k < 16; ++k) {
            float4 a4 = *(const float4*)&As[k][ty << 2];
            float4 b4 = *(const float4*)&Bs[k][tx << 2];
            float aa[4] = {a4.x, a4.y, a4.z, a4.w};
            float bb[4] = {b4.x, b4.y, b4.z, b4.w};
            #pragma unroll
            for (int i = 0; i < 4; ++i)
                #pragma unroll
                for (int j = 0; j < 4; ++j)
                    acc[i][j] = fmaf(aa[i], bb[j], acc[i][j]);
        }
    }

    float bj[4];
    #pragma unroll
    for (int j = 0; j < 4; ++j) bj[j] = bias[d0 + tx * 4 + j];
    #pragma unroll
    for (int i = 0; i < 4; ++i) {
        #pragma unroll
        for (int j = 0; j < 4; ++j) {
            float v = acc[i][j] + bj[j];
            v = fminf(fmaxf(v, -15.f), 15.f);   // guard exp overflow; tanh saturated anyway
            float e = __expf(2.f * v);
            int r = r0 + ty * 4 + i, d = d0 + tx * 4 + j;
            if (mat == 0) Eq[r * DD + d]  = e;
            else          EkT[d * MM + r] = e;
        }
    }
}

// ---------------- Kernel 2: scores + softmax_M + context + stage-2 score ----------------
// s~[n,m] = sum_d (-2 w[d]) * rcp(Eq[n,d]*Ek[m,d] + 1)   (softmax-equivalent to ref scores)
__global__ __launch_bounds__(256) void attn_ctx_kernel(
    const float* __restrict__ Eq, const float* __restrict__ EkT,
    const float* __restrict__ frp, const float* __restrict__ w_w,
    const float* __restrict__ wp_w,
    float* __restrict__ ctx, float* __restrict__ score)
{
    __shared__ float eq0[DD], eq1[DD], w2[DD];
    __shared__ float al0[MM], al1[MM];
    __shared__ float red[32];

    const int t = threadIdx.x;
    const int lane = t & 63, wid = t >> 6;
    const int n0 = blockIdx.x * 2, n1 = n0 + 1;

    eq0[t] = Eq[n0 * DD + t];
    eq1[t] = Eq[n1 * DD + t];
    w2[t]  = -2.0f * w_w[t];
    __syncthreads();

    float acc0[4] = {0.f, 0.f, 0.f, 0.f};
    float acc1[4] = {0.f, 0.f, 0.f, 0.f};

    const float4* eq0v = (const float4*)eq0;
    const float4* eq1v = (const float4*)eq1;
    const float4* w2v  = (const float4*)w2;
    const float* kp = EkT + t;   // thread t handles m = t + 256*j

    for (int d4 = 0; d4 < DD / 4; ++d4) {
        float4 qa4 = eq0v[d4];
        float4 qb4 = eq1v[d4];
        float4 wv4 = w2v[d4];
        float qa[4] = {qa4.x, qa4.y, qa4.z, qa4.w};
        float qb[4] = {qb4.x, qb4.y, qb4.z, qb4.w};
        float wv[4] = {wv4.x, wv4.y, wv4.z, wv4.w};
        const float* kd = kp + (d4 * 4) * MM;
        #pragma unroll
        for (int dd = 0; dd < 4; ++dd) {
            #pragma unroll
            for (int j = 0; j < 4; ++j) {
                float kv  = kd[dd * MM + j * 256];
                float r0v = rcp_fast(fmaf(qa[dd], kv, 1.0f));
                float r1v = rcp_fast(fmaf(qb[dd], kv, 1.0f));
                acc0[j] = fmaf(wv[dd], r0v, acc0[j]);
                acc1[j] = fmaf(wv[dd], r1v, acc1[j]);
            }
        }
    }

    // ---- softmax over m (1024 values/n, 4 per thread) ----
    float mx0 = fmaxf(fmaxf(acc0[0], acc0[1]), fmaxf(acc0[2], acc0[3]));
    float mx1 = fmaxf(fmaxf(acc1[0], acc1[1]), fmaxf(acc1[2], acc1[3]));
    #pragma unroll
    for (int off = 32; off > 0; off >>= 1) {
        mx0 = fmaxf(mx0, __shfl_xor(mx0, off));
        mx1 = fmaxf(mx1, __shfl_xor(mx1, off));
    }
    if (lane == 0) { red[wid] = mx0; red[4 + wid] = mx1; }
    __syncthreads();
    mx0 = fmaxf(fmaxf(red[0], red[1]), fmaxf(red[2], red[3]));
    mx1 = fmaxf(fmaxf(red[4], red[5]), fmaxf(red[6], red[7]));

    float e0[4], e1[4];
    float s0 = 0.f, s1 = 0.f;
    #pragma unroll
    for (int j = 0; j < 4; ++j) {
        e0[j] = __expf(acc0[j] - mx0); s0 += e0[j];
        e1[j] = __expf(acc1[j] - mx1); s1 += e1[j];
    }
    #pragma unroll
    for (int off = 32; off > 0; off >>= 1) { s0 += __shfl_xor(s0, off); s1 += __shfl_xor(s1, off); }
    if (lane == 0) { red[8 + wid] = s0; red[12 + wid] = s1; }
    #pragma unroll
    for (int j = 0; j < 4; ++j) { al0[t + 256 * j] = e0[j]; al1[t + 256 * j] = e1[j]; }
    __syncthreads();
    float inv0 = rcp_fast(red[8]  + red[9]  + red[10] + red[11]);
    float inv1 = rcp_fast(red[12] + red[13] + red[14] + red[15]);

    // ---- context[n, t] = (sum_m e_m * frp[m, t]) * inv_denom ----
    float c0 = 0.f, c1 = 0.f;
    const float4* al0v = (const float4*)al0;
    const float4* al1v = (const float4*)al1;
    const float* fb = frp + t;
    for (int m4 = 0; m4 < MM / 4; ++m4) {
        float4 a04 = al0v[m4];
        float4 a14 = al1v[m4];
        float a0[4] = {a04.x, a04.y, a04.z, a04.w};
        float a1[4] = {a14.x, a14.y, a14.z, a14.w};
        const float* fm = fb + (m4 * 4) * DD;
        #pragma unroll
        for (int dd = 0; dd < 4; ++dd) {
            float v = fm[dd * DD];
            c0 = fmaf(a0[dd], v, c0);
            c1 = fmaf(a1[dd], v, c1);
        }
    }
    c0 *= inv0; c1 *= inv1;
    ctx[n0 * DD + t] = c0;
    ctx[n1 * DD + t] = c1;

    // ---- stage-2 raw score[n] = dot(ctx_row, wp_w)  (wp_b cancels in softmax) ----
    float wpv = wp_w[t];
    float p0 = c0 * wpv, p1 = c1 * wpv;
    #pragma unroll
    for (int off = 32; off > 0; off >>= 1) { p0 += __shfl_xor(p0, off); p1 += __shfl_xor(p1, off); }
    if (lane == 0) { red[16 + wid] = p0; red[20 + wid] = p1; }
    __syncthreads();
    if (t == 0) score[n0] = red[16] + red[17] + red[18] + red[19];
    if (t == 1) score[n1] = red[20] + red[21] + red[22] + red[23];
}

// ---------------- Kernel 3: softmax over N + pooled sum ----------------
__global__ __launch_bounds__(256) void pool_kernel(
    const float* __restrict__ ctx, const float* __restrict__ score,
    float* __restrict__ out)
{
    __shared__ float red[8];
    __shared__ float wloc[16];
    const int t = threadIdx.x, lane = t & 63, wid = t >> 6;

    float s0 = score[t], s1 = score[t + 256], s2 = score[t + 512], s3 = score[t + 768];
    float mx = fmaxf(fmaxf(s0, s1), fmaxf(s2, s3));
    #pragma unroll
    for (int off = 32; off > 0; off >>= 1) mx = fmaxf(mx, __shfl_xor(mx, off));
    if (lane == 0) red[wid] = mx;
    __syncthreads();
    mx = fmaxf(fmaxf(red[0], red[1]), fmaxf(red[2], red[3]));

    float se = __expf(s0 - mx) + __expf(s1 - mx) + __expf(s2 - mx) + __expf(s3 - mx);
    #pragma unroll
    for (int off = 32; off > 0; off >>= 1) se += __shfl_xor(se, off);
    if (lane == 0) red[4 + wid] = se;
    __syncthreads();
    se = red[4] + red[5] + red[6] + red[7];
    float invS = rcp_fast(se);

    if (t < 16) wloc[t] = __expf(score[blockIdx.x * 16 + t] - mx) * invS;
    __syncthreads();

    float pool = 0.f;
    const float* cb = ctx + (blockIdx.x * 16) * DD + t;
    #pragma unroll
    for (int i = 0; i < 16; ++i) pool = fmaf(wloc[i], cb[i * DD], pool);
    atomicAdd(out + t, pool);
}

extern "C" void kernel_launch(void* const* d_in, const int* in_sizes, int n_in,
                              void* d_out, int out_size, void* d_ws, size_t ws_size,
                              hipStream_t stream) {
    const float* f_r   = (const float*)d_in[0];
    const float* f_rp  = (const float*)d_in[1];
    const float* W_w   = (const float*)d_in[2];
    const float* W_b   = (const float*)d_in[3];
    const float* Wp_w  = (const float*)d_in[4];
    const float* Wp_b  = (const float*)d_in[5];
    const float* w_w   = (const float*)d_in[6];
    // d_in[7] = w_b   : cancels in softmax over m
    const float* wp_w  = (const float*)d_in[8];
    // d_in[9] = wp_b  : cancels in softmax over n
    float* out = (float*)d_out;

    float* ws    = (float*)d_ws;
    float* Eq    = ws;                       // [1024][256]
    float* EkT   = ws + 1 * NN * DD;         // [256][1024]
    float* ctx   = ws + 2 * NN * DD;         // [1024][256]
    float* score = ws + 3 * NN * DD;         // [1024]

    hipMemsetAsync(d_out, 0, DD * sizeof(float), stream);
    gemm_exp_kernel<<<128, 256, 0, stream>>>(f_r, W_w, W_b, f_rp, Wp_w, Wp_b, Eq, EkT);
    attn_ctx_kernel<<<512, 256, 0, stream>>>(Eq, EkT, f_rp, w_w, wp_w, ctx, score);
    pool_kernel<<<64, 256, 0, stream>>>(ctx, score, out);
}

// Round 2
// 152.509 us; speedup vs baseline: 1.0145x; 1.0145x over previous
//
#include <hip/hip_runtime.h>

#define NN 1024
#define MM 1024
#define DD 256

__device__ __forceinline__ float rcp_fast(float x) { return __builtin_amdgcn_rcpf(x); }

// ---------------- K1: fused dual GEMM + exp epilogue ----------------
// q = f_r @ W_w^T + W_b      -> Eq[n][d]  = exp(2q)
// k = f_rp @ Wp_w^T + Wp_b   -> EkT[d][m] = exp(2k)  (transposed via LDS, coalesced stores)
// 32x64 tiles: 32 r-tiles x 4 d-tiles x 2 mats = 256 blocks (1 per CU).
__global__ __launch_bounds__(256) void gemm_exp_kernel(
    const float* __restrict__ f_r,  const float* __restrict__ W_w,  const float* __restrict__ W_b,
    const float* __restrict__ f_rp, const float* __restrict__ Wp_w, const float* __restrict__ Wp_b,
    float* __restrict__ Eq, float* __restrict__ EkT)
{
    const int b    = blockIdx.x;
    const int mat  = b >> 7;
    const int tile = b & 127;
    const int rt = tile & 31, dt = tile >> 5;
    const float* __restrict__ A    = mat ? f_rp : f_r;
    const float* __restrict__ B    = mat ? Wp_w : W_w;
    const float* __restrict__ bias = mat ? Wp_b : W_b;

    __shared__ float As[32][36];   // [k][r]
    __shared__ float Bs[32][68];   // [k][d]
    __shared__ float T[64][36];    // k-path transpose buffer [d_local][r_local]

    const int t  = threadIdx.x;
    const int tx = t & 15, ty = t >> 4;          // tx -> 4 d-cols, ty -> 2 r-rows
    const int r0 = rt * 32, d0 = dt * 64;
    const int ar = t >> 3, ak = (t & 7) * 4;     // A stage: 32 rows x 32 k
    const int br = t >> 2, bk = (t & 3) * 8;     // B stage: 64 rows x 32 k

    float acc[2][4];
    #pragma unroll
    for (int i = 0; i < 2; ++i)
        #pragma unroll
        for (int j = 0; j < 4; ++j) acc[i][j] = 0.f;

    for (int kk = 0; kk < DD; kk += 32) {
        float4 av  = *(const float4*)(A + (size_t)(r0 + ar) * DD + kk + ak);
        float4 bv0 = *(const float4*)(B + (size_t)(d0 + br) * DD + kk + bk);
        float4 bv1 = *(const float4*)(B + (size_t)(d0 + br) * DD + kk + bk + 4);
        __syncthreads();
        As[ak + 0][ar] = av.x; As[ak + 1][ar] = av.y; As[ak + 2][ar] = av.z; As[ak + 3][ar] = av.w;
        Bs[bk + 0][br] = bv0.x; Bs[bk + 1][br] = bv0.y; Bs[bk + 2][br] = bv0.z; Bs[bk + 3][br] = bv0.w;
        Bs[bk + 4][br] = bv1.x; Bs[bk + 5][br] = bv1.y; Bs[bk + 6][br] = bv1.z; Bs[bk + 7][br] = bv1.w;
        __syncthreads();
        #pragma unroll
        for (int k = 0; k < 32; ++k) {
            float2 a2 = *(const float2*)&As[k][ty * 2];
            float4 b4 = *(const float4*)&Bs[k][tx * 4];
            float aa[2] = {a2.x, a2.y};
            float bb[4] = {b4.x, b4.y, b4.z, b4.w};
            #pragma unroll
            for (int i = 0; i < 2; ++i)
                #pragma unroll
                for (int j = 0; j < 4; ++j)
                    acc[i][j] = fmaf(aa[i], bb[j], acc[i][j]);
        }
    }

    float bj[4];
    #pragma unroll
    for (int j = 0; j < 4; ++j) bj[j] = bias[d0 + tx * 4 + j];

    float e[2][4];
    #pragma unroll
    for (int i = 0; i < 2; ++i)
        #pragma unroll
        for (int j = 0; j < 4; ++j) {
            float v = acc[i][j] + bj[j];
            v = fminf(fmaxf(v, -15.f), 15.f);   // tanh saturated anyway; guards exp overflow
            e[i][j] = __expf(2.f * v);
        }

    if (mat == 0) {
        #pragma unroll
        for (int i = 0; i < 2; ++i)
            *(float4*)&Eq[(size_t)(r0 + ty * 2 + i) * DD + d0 + tx * 4] =
                make_float4(e[i][0], e[i][1], e[i][2], e[i][3]);
    } else {
        __syncthreads();
        #pragma unroll
        for (int i = 0; i < 2; ++i)
            #pragma unroll
            for (int j = 0; j < 4; ++j) T[tx * 4 + j][ty * 2 + i] = e[i][j];
        __syncthreads();
        const int dl = t >> 3, rl = (t & 7) * 4;
        #pragma unroll
        for (int h = 0; h < 2; ++h) {
            int dloc = dl + 32 * h;
            float4 tv = *(const float4*)&T[dloc][rl];
            *(float4*)&EkT[(size_t)(d0 + dloc) * MM + r0 + rl] = tv;
        }
    }
}

// ---------------- K2a: scores + softmax over m -> alpha ----------------
// s~[n,m] = sum_d (-2 w[d]) * rcp(Eq[n,d]*Ek[m,d] + 1)
// 256 blocks x 512 thr; block = 4 n-rows; tg = d-half (0..127 / 128..255);
// tm = t&255 -> m cols 4tm..4tm+3 (float4 loads from EkT).
__global__ __launch_bounds__(512) void score_softmax_kernel(
    const float* __restrict__ Eq, const float* __restrict__ EkT,
    const float* __restrict__ w_w, float* __restrict__ alpha)
{
    __shared__ float eq[4 * DD];       // 4 rows of Eq
    __shared__ float w2[DD];
    __shared__ float accbuf[16][256];  // d-half combine, [comp][tm] conflict-free
    __shared__ float redmx[8 * 4];
    __shared__ float redsm[8 * 4];

    const int t  = threadIdx.x;
    const int tg = t >> 8;
    const int tm = t & 255;
    const int lane = t & 63, wid = t >> 6;
    const int n0 = blockIdx.x * 4;
    const int dh = tg * 128;

    eq[t]       = Eq[(size_t)n0 * DD + t];
    eq[t + 512] = Eq[(size_t)n0 * DD + 512 + t];
    if (t < DD) w2[t] = -2.0f * w_w[t];
    __syncthreads();

    float acc[4][4];
    #pragma unroll
    for (int n = 0; n < 4; ++n)
        #pragma unroll
        for (int j = 0; j < 4; ++j) acc[n][j] = 0.f;

    const float* ekb = EkT + (size_t)dh * MM + 4 * tm;

    for (int g = 0; g < 32; ++g) {
        const int db = g * 4;
        float4 k4[4];
        #pragma unroll
        for (int dd = 0; dd < 4; ++dd)
            k4[dd] = *(const float4*)(ekb + (size_t)(db + dd) * MM);
        float4 w4 = *(const float4*)&w2[dh + db];
        float4 q4[4];
        #pragma unroll
        for (int n = 0; n < 4; ++n) q4[n] = *(const float4*)&eq[n * DD + dh + db];

        float wv[4] = {w4.x, w4.y, w4.z, w4.w};
        float kv[4][4], qv[4][4];
        #pragma unroll
        for (int dd = 0; dd < 4; ++dd) {
            kv[dd][0] = k4[dd].x; kv[dd][1] = k4[dd].y; kv[dd][2] = k4[dd].z; kv[dd][3] = k4[dd].w;
        }
        #pragma unroll
        for (int n = 0; n < 4; ++n) {
            qv[n][0] = q4[n].x; qv[n][1] = q4[n].y; qv[n][2] = q4[n].z; qv[n][3] = q4[n].w;
        }
        #pragma unroll
        for (int dd = 0; dd < 4; ++dd)
            #pragma unroll
            for (int n = 0; n < 4; ++n)
                #pragma unroll
                for (int j = 0; j < 4; ++j)
                    acc[n][j] = fmaf(wv[dd], rcp_fast(fmaf(qv[n][dd], kv[dd][j], 1.f)), acc[n][j]);
    }

    // combine d-halves: tg1 -> LDS, tg0 adds
    if (tg == 1) {
        #pragma unroll
        for (int n = 0; n < 4; ++n)
            #pragma unroll
            for (int j = 0; j < 4; ++j) accbuf[n * 4 + j][tm] = acc[n][j];
    }
    __syncthreads();
    if (tg == 0) {
        #pragma unroll
        for (int n = 0; n < 4; ++n)
            #pragma unroll
            for (int j = 0; j < 4; ++j) acc[n][j] += accbuf[n * 4 + j][tm];
    }

    // softmax over m: max
    float mx[4];
    #pragma unroll
    for (int n = 0; n < 4; ++n) {
        mx[n] = (tg == 0) ? fmaxf(fmaxf(acc[n][0], acc[n][1]), fmaxf(acc[n][2], acc[n][3])) : -1e30f;
        #pragma unroll
        for (int off = 32; off > 0; off >>= 1) mx[n] = fmaxf(mx[n], __shfl_xor(mx[n], off));
    }
    if (lane == 0)
        #pragma unroll
        for (int n = 0; n < 4; ++n) redmx[wid * 4 + n] = mx[n];
    __syncthreads();
    float MX[4];
    #pragma unroll
    for (int n = 0; n < 4; ++n) {
        float m = redmx[n];
        #pragma unroll
        for (int w = 1; w < 8; ++w) m = fmaxf(m, redmx[w * 4 + n]);
        MX[n] = m;
    }

    // exp + sum
    float e[4][4], sm[4];
    #pragma unroll
    for (int n = 0; n < 4; ++n) {
        sm[n] = 0.f;
        #pragma unroll
        for (int j = 0; j < 4; ++j) {
            e[n][j] = (tg == 0) ? __expf(acc[n][j] - MX[n]) : 0.f;
            sm[n] += e[n][j];
        }
        #pragma unroll
        for (int off = 32; off > 0; off >>= 1) sm[n] += __shfl_xor(sm[n], off);
    }
    if (lane == 0)
        #pragma unroll
        for (int n = 0; n < 4; ++n) redsm[wid * 4 + n] = sm[n];
    __syncthreads();
    if (tg == 0) {
        #pragma unroll
        for (int n = 0; n < 4; ++n) {
            float s = redsm[n];
            #pragma unroll
            for (int w = 1; w < 8; ++w) s += redsm[w * 4 + n];
            float inv = rcp_fast(s);
            *(float4*)&alpha[(size_t)(n0 + n) * MM + 4 * tm] =
                make_float4(e[n][0] * inv, e[n][1] * inv, e[n][2] * inv, e[n][3] * inv);
        }
    }
}

// ---------------- K2b: context GEMM, part[ms] = alpha_tile @ frp_tile ----------------
// tile: 16 n x 256 d, m-split 4 -> 64 x 4 = 256 blocks x 256 thr.
__global__ __launch_bounds__(256) void context_kernel(
    const float* __restrict__ alpha, const float* __restrict__ frp,
    float* __restrict__ part)
{
    __shared__ float als[16][256];   // alpha tile, broadcast reads (wave-uniform row)
    const int t  = threadIdx.x;
    const int bm = blockIdx.x & 3;
    const int bn = blockIdx.x >> 2;
    const int dq = t & 63;           // 4 d-cols: 4dq..4dq+3
    const int ng = t >> 6;           // n-subgroup (== wave id -> broadcast)

    #pragma unroll
    for (int i = 0; i < 4; ++i) {
        int f4i = t + i * 256;
        int row = f4i >> 6, c4 = f4i & 63;
        *(float4*)&als[row][c4 * 4] =
            *(const float4*)&alpha[(size_t)(bn * 16 + row) * MM + bm * 256 + c4 * 4];
    }
    __syncthreads();

    float acc[4][4];
    #pragma unroll
    for (int n = 0; n < 4; ++n)
        #pragma unroll
        for (int j = 0; j < 4; ++j) acc[n][j] = 0.f;

    const float* fb = frp + (size_t)(bm * 256) * DD + 4 * dq;
    for (int m4 = 0; m4 < 64; ++m4) {
        float av[4][4];
        #pragma unroll
        for (int n = 0; n < 4; ++n) {
            float4 a4 = *(const float4*)&als[ng * 4 + n][m4 * 4];
            av[n][0] = a4.x; av[n][1] = a4.y; av[n][2] = a4.z; av[n][3] = a4.w;
        }
        #pragma unroll
        for (int mm = 0; mm < 4; ++mm) {
            float4 f4 = *(const float4*)(fb + (size_t)(m4 * 4 + mm) * DD);
            float fv[4] = {f4.x, f4.y, f4.z, f4.w};
            #pragma unroll
            for (int n = 0; n < 4; ++n)
                #pragma unroll
                for (int j = 0; j < 4; ++j)
                    acc[n][j] = fmaf(av[n][mm], fv[j], acc[n][j]);
        }
    }
    #pragma unroll
    for (int n = 0; n < 4; ++n)
        *(float4*)&part[((size_t)bm << 18) + (size_t)(bn * 16 + ng * 4 + n) * DD + 4 * dq] =
            make_float4(acc[n][0], acc[n][1], acc[n][2], acc[n][3]);
}

// ---------------- K2c: reduce m-split partials -> ctx, stage-2 raw scores ----------------
__global__ __launch_bounds__(256) void ctx_reduce_kernel(
    const float* __restrict__ part, const float* __restrict__ wp_w,
    float* __restrict__ ctx, float* __restrict__ score)
{
    __shared__ float red[4];
    const int t = threadIdx.x;
    const int n = blockIdx.x;
    const int lane = t & 63, wid = t >> 6;
    size_t idx = (size_t)n * DD + t;
    float c = part[idx] + part[idx + (1u << 18)] + part[idx + (2u << 18)] + part[idx + (3u << 18)];
    ctx[idx] = c;
    float p = c * wp_w[t];
    #pragma unroll
    for (int off = 32; off > 0; off >>= 1) p += __shfl_xor(p, off);
    if (lane == 0) red[wid] = p;
    __syncthreads();
    if (t == 0) score[n] = red[0] + red[1] + red[2] + red[3];
}

// ---------------- K3: softmax over N + pooled sum ----------------
__global__ __launch_bounds__(256) void pool_kernel(
    const float* __restrict__ ctx, const float* __restrict__ score,
    float* __restrict__ out)
{
    __shared__ float red[8];
    __shared__ float wloc[16];
    const int t = threadIdx.x, lane = t & 63, wid = t >> 6;

    float s0 = score[t], s1 = score[t + 256], s2 = score[t + 512], s3 = score[t + 768];
    float mx = fmaxf(fmaxf(s0, s1), fmaxf(s2, s3));
    #pragma unroll
    for (int off = 32; off > 0; off >>= 1) mx = fmaxf(mx, __shfl_xor(mx, off));
    if (lane == 0) red[wid] = mx;
    __syncthreads();
    mx = fmaxf(fmaxf(red[0], red[1]), fmaxf(red[2], red[3]));

    float se = __expf(s0 - mx) + __expf(s1 - mx) + __expf(s2 - mx) + __expf(s3 - mx);
    #pragma unroll
    for (int off = 32; off > 0; off >>= 1) se += __shfl_xor(se, off);
    if (lane == 0) red[4 + wid] = se;
    __syncthreads();
    se = red[4] + red[5] + red[6] + red[7];
    float invS = rcp_fast(se);

    if (t < 16) wloc[t] = __expf(score[blockIdx.x * 16 + t] - mx) * invS;
    __syncthreads();

    float pool = 0.f;
    const float* cb = ctx + (size_t)(blockIdx.x * 16) * DD + t;
    #pragma unroll
    for (int i = 0; i < 16; ++i) pool = fmaf(wloc[i], cb[i * DD], pool);
    atomicAdd(out + t, pool);
}

extern "C" void kernel_launch(void* const* d_in, const int* in_sizes, int n_in,
                              void* d_out, int out_size, void* d_ws, size_t ws_size,
                              hipStream_t stream) {
    const float* f_r  = (const float*)d_in[0];
    const float* f_rp = (const float*)d_in[1];
    const float* W_w  = (const float*)d_in[2];
    const float* W_b  = (const float*)d_in[3];
    const float* Wp_w = (const float*)d_in[4];
    const float* Wp_b = (const float*)d_in[5];
    const float* w_w  = (const float*)d_in[6];
    // d_in[7] = w_b  : cancels in softmax over m
    const float* wp_w = (const float*)d_in[8];
    // d_in[9] = wp_b : cancels in softmax over n
    float* out = (float*)d_out;

    float* ws    = (float*)d_ws;
    float* Eq    = ws;                  // 256K floats
    float* EkT   = ws + 262144;         // 256K
    float* alpha = ws + 524288;         // 1M
    float* part  = ws + 1572864;        // 4 x 256K
    float* ctx   = ws + 2621440;        // 256K
    float* score = ws + 2883584;        // 1K

    hipMemsetAsync(d_out, 0, DD * sizeof(float), stream);
    gemm_exp_kernel<<<256, 256, 0, stream>>>(f_r, W_w, W_b, f_rp, Wp_w, Wp_b, Eq, EkT);
    score_softmax_kernel<<<256, 512, 0, stream>>>(Eq, EkT, w_w, alpha);
    context_kernel<<<256, 256, 0, stream>>>(alpha, f_rp, part);
    ctx_reduce_kernel<<<1024, 256, 0, stream>>>(part, wp_w, ctx, score);
    pool_kernel<<<64, 256, 0, stream>>>(ctx, score, out);
}

// Round 3
// 135.291 us; speedup vs baseline: 1.1436x; 1.1273x over previous
//
#include <hip/hip_runtime.h>

#define NN 1024
#define MM 1024
#define DD 256

__device__ __forceinline__ float rcp_fast(float x) { return __builtin_amdgcn_rcpf(x); }

// ---------------- K1: fused dual GEMM + exp epilogue ----------------
// q = f_r @ W_w^T + W_b      -> Eq[n][d]  = exp(2q)
// k = f_rp @ Wp_w^T + Wp_b   -> EkT[d][m] = exp(2k)  (transposed via LDS, coalesced stores)
// Also zeroes d_out (block 0) so pool_kernel can atomicAdd.
__global__ __launch_bounds__(256) void gemm_exp_kernel(
    const float* __restrict__ f_r,  const float* __restrict__ W_w,  const float* __restrict__ W_b,
    const float* __restrict__ f_rp, const float* __restrict__ Wp_w, const float* __restrict__ Wp_b,
    float* __restrict__ Eq, float* __restrict__ EkT, float* __restrict__ out0)
{
    const int b    = blockIdx.x;
    const int mat  = b >> 7;
    const int tile = b & 127;
    const int rt = tile & 31, dt = tile >> 5;
    const float* __restrict__ A    = mat ? f_rp : f_r;
    const float* __restrict__ B    = mat ? Wp_w : W_w;
    const float* __restrict__ bias = mat ? Wp_b : W_b;

    __shared__ float As[32][36];   // [k][r]
    __shared__ float Bs[32][68];   // [k][d]
    __shared__ float T[64][36];    // k-path transpose buffer [d_local][r_local]

    const int t  = threadIdx.x;
    if (b == 0) out0[t] = 0.f;     // zero d_out for pool's atomicAdd
    const int tx = t & 15, ty = t >> 4;          // tx -> 4 d-cols, ty -> 2 r-rows
    const int r0 = rt * 32, d0 = dt * 64;
    const int ar = t >> 3, ak = (t & 7) * 4;     // A stage: 32 rows x 32 k
    const int br = t >> 2, bk = (t & 3) * 8;     // B stage: 64 rows x 32 k

    float acc[2][4];
    #pragma unroll
    for (int i = 0; i < 2; ++i)
        #pragma unroll
        for (int j = 0; j < 4; ++j) acc[i][j] = 0.f;

    for (int kk = 0; kk < DD; kk += 32) {
        float4 av  = *(const float4*)(A + (size_t)(r0 + ar) * DD + kk + ak);
        float4 bv0 = *(const float4*)(B + (size_t)(d0 + br) * DD + kk + bk);
        float4 bv1 = *(const float4*)(B + (size_t)(d0 + br) * DD + kk + bk + 4);
        __syncthreads();
        As[ak + 0][ar] = av.x; As[ak + 1][ar] = av.y; As[ak + 2][ar] = av.z; As[ak + 3][ar] = av.w;
        Bs[bk + 0][br] = bv0.x; Bs[bk + 1][br] = bv0.y; Bs[bk + 2][br] = bv0.z; Bs[bk + 3][br] = bv0.w;
        Bs[bk + 4][br] = bv1.x; Bs[bk + 5][br] = bv1.y; Bs[bk + 6][br] = bv1.z; Bs[bk + 7][br] = bv1.w;
        __syncthreads();
        #pragma unroll
        for (int k = 0; k < 32; ++k) {
            float2 a2 = *(const float2*)&As[k][ty * 2];
            float4 b4 = *(const float4*)&Bs[k][tx * 4];
            float aa[2] = {a2.x, a2.y};
            float bb[4] = {b4.x, b4.y, b4.z, b4.w};
            #pragma unroll
            for (int i = 0; i < 2; ++i)
                #pragma unroll
                for (int j = 0; j < 4; ++j)
                    acc[i][j] = fmaf(aa[i], bb[j], acc[i][j]);
        }
    }

    float bj[4];
    #pragma unroll
    for (int j = 0; j < 4; ++j) bj[j] = bias[d0 + tx * 4 + j];

    float e[2][4];
    #pragma unroll
    for (int i = 0; i < 2; ++i)
        #pragma unroll
        for (int j = 0; j < 4; ++j) {
            float v = acc[i][j] + bj[j];
            // +-10: tanh fully saturated; keeps pair-products (e^40)^2 < fp32 max
            v = fminf(fmaxf(v, -10.f), 10.f);
            e[i][j] = __expf(2.f * v);
        }

    if (mat == 0) {
        #pragma unroll
        for (int i = 0; i < 2; ++i)
            *(float4*)&Eq[(size_t)(r0 + ty * 2 + i) * DD + d0 + tx * 4] =
                make_float4(e[i][0], e[i][1], e[i][2], e[i][3]);
    } else {
        __syncthreads();
        #pragma unroll
        for (int i = 0; i < 2; ++i)
            #pragma unroll
            for (int j = 0; j < 4; ++j) T[tx * 4 + j][ty * 2 + i] = e[i][j];
        __syncthreads();
        const int dl = t >> 3, rl = (t & 7) * 4;
        #pragma unroll
        for (int h = 0; h < 2; ++h) {
            int dloc = dl + 32 * h;
            float4 tv = *(const float4*)&T[dloc][rl];
            *(float4*)&EkT[(size_t)(d0 + dloc) * MM + r0 + rl] = tv;
        }
    }
}

// ---------------- K2a: scores + softmax over m -> alpha ----------------
// s~[n,m] = sum_d (-2 w[d]) * rcp(Eq[n,d]*Ek[m,d] + 1)
// Pairwise: w0/x0 + w1/x1 = (w0*x1 + w1*x0) * rcp(x0*x1)  -> half the rcp count.
// 512 blocks x 512 thr; block = 2 n-rows; tg = d-half; tm -> m cols 4tm..4tm+3.
__global__ __launch_bounds__(512, 8) void score_softmax_kernel(
    const float* __restrict__ Eq, const float* __restrict__ EkT,
    const float* __restrict__ w_w, float* __restrict__ alpha)
{
    __shared__ float eq[2 * DD];
    __shared__ float w2[DD];
    __shared__ float accbuf[8][256];
    __shared__ float redmx[8 * 2];
    __shared__ float redsm[8 * 2];

    const int t  = threadIdx.x;
    const int tg = t >> 8;        // d-half
    const int tm = t & 255;       // m cols 4tm..4tm+3
    const int lane = t & 63, wid = t >> 6;
    const int n0 = blockIdx.x * 2;
    const int dh = tg * 128;

    eq[t] = Eq[(size_t)n0 * DD + t];
    if (t < DD) w2[t] = -2.0f * w_w[t];
    __syncthreads();

    float acc[2][4];
    #pragma unroll
    for (int n = 0; n < 2; ++n)
        #pragma unroll
        for (int j = 0; j < 4; ++j) acc[n][j] = 0.f;

    const float* ekb = EkT + (size_t)dh * MM + 4 * tm;

    for (int g = 0; g < 32; ++g) {
        const int db = g * 4;
        float4 k0 = *(const float4*)(ekb + (size_t)(db + 0) * MM);
        float4 k1 = *(const float4*)(ekb + (size_t)(db + 1) * MM);
        float4 k2 = *(const float4*)(ekb + (size_t)(db + 2) * MM);
        float4 k3 = *(const float4*)(ekb + (size_t)(db + 3) * MM);
        float4 w4 = *(const float4*)&w2[dh + db];
        float4 qA = *(const float4*)&eq[dh + db];
        float4 qB = *(const float4*)&eq[DD + dh + db];

        float ka[2][4] = {{k0.x, k0.y, k0.z, k0.w}, {k2.x, k2.y, k2.z, k2.w}};
        float kb[2][4] = {{k1.x, k1.y, k1.z, k1.w}, {k3.x, k3.y, k3.z, k3.w}};
        float wa[2] = {w4.x, w4.z}, wb[2] = {w4.y, w4.w};
        float qa[2][2] = {{qA.x, qA.z}, {qB.x, qB.z}};   // [n][pair]
        float qb[2][2] = {{qA.y, qA.w}, {qB.y, qB.w}};

        #pragma unroll
        for (int pp = 0; pp < 2; ++pp)
            #pragma unroll
            for (int n = 0; n < 2; ++n)
                #pragma unroll
                for (int j = 0; j < 4; ++j) {
                    float x0 = fmaf(qa[n][pp], ka[pp][j], 1.f);
                    float x1 = fmaf(qb[n][pp], kb[pp][j], 1.f);
                    float p  = x0 * x1;
                    float tn = fmaf(wb[pp], x0, wa[pp] * x1);
                    acc[n][j] = fmaf(tn, rcp_fast(p), acc[n][j]);
                }
    }

    // combine d-halves
    if (tg == 1) {
        #pragma unroll
        for (int n = 0; n < 2; ++n)
            #pragma unroll
            for (int j = 0; j < 4; ++j) accbuf[n * 4 + j][tm] = acc[n][j];
    }
    __syncthreads();
    if (tg == 0) {
        #pragma unroll
        for (int n = 0; n < 2; ++n)
            #pragma unroll
            for (int j = 0; j < 4; ++j) acc[n][j] += accbuf[n * 4 + j][tm];
    }

    // softmax over m: max
    float mx[2];
    #pragma unroll
    for (int n = 0; n < 2; ++n) {
        mx[n] = (tg == 0) ? fmaxf(fmaxf(acc[n][0], acc[n][1]), fmaxf(acc[n][2], acc[n][3])) : -3e38f;
        #pragma unroll
        for (int off = 32; off > 0; off >>= 1) mx[n] = fmaxf(mx[n], __shfl_xor(mx[n], off));
    }
    if (lane == 0) { redmx[wid * 2] = mx[0]; redmx[wid * 2 + 1] = mx[1]; }
    __syncthreads();
    float MX[2];
    #pragma unroll
    for (int n = 0; n < 2; ++n) {
        float m = redmx[n];
        #pragma unroll
        for (int w = 1; w < 8; ++w) m = fmaxf(m, redmx[w * 2 + n]);
        MX[n] = m;
    }

    // exp + sum
    float e[2][4], sm[2];
    #pragma unroll
    for (int n = 0; n < 2; ++n) {
        sm[n] = 0.f;
        #pragma unroll
        for (int j = 0; j < 4; ++j) {
            e[n][j] = (tg == 0) ? __expf(acc[n][j] - MX[n]) : 0.f;
            sm[n] += e[n][j];
        }
        #pragma unroll
        for (int off = 32; off > 0; off >>= 1) sm[n] += __shfl_xor(sm[n], off);
    }
    if (lane == 0) { redsm[wid * 2] = sm[0]; redsm[wid * 2 + 1] = sm[1]; }
    __syncthreads();
    if (tg == 0) {
        #pragma unroll
        for (int n = 0; n < 2; ++n) {
            float s = redsm[n];
            #pragma unroll
            for (int w = 1; w < 8; ++w) s += redsm[w * 2 + n];
            float inv = rcp_fast(s);
            *(float4*)&alpha[(size_t)(n0 + n) * MM + 4 * tm] =
                make_float4(e[n][0] * inv, e[n][1] * inv, e[n][2] * inv, e[n][3] * inv);
        }
    }
}

// ---------------- K2b: context GEMM, part[ms] = alpha_tile @ frp_tile ----------------
// tile: 16 n x 256 d, m-split 8 -> 64 x 8 = 512 blocks x 256 thr.
__global__ __launch_bounds__(256) void context_kernel(
    const float* __restrict__ alpha, const float* __restrict__ frp,
    float* __restrict__ part)
{
    __shared__ float als[16][128];   // alpha tile, broadcast reads (wave-uniform row)
    const int t  = threadIdx.x;
    const int bm = blockIdx.x & 7;
    const int bn = blockIdx.x >> 3;
    const int dq = t & 63;           // 4 d-cols: 4dq..4dq+3
    const int ng = t >> 6;           // n-subgroup (== wave id -> broadcast)

    #pragma unroll
    for (int i = 0; i < 2; ++i) {
        int f4i = t + i * 256;
        int row = f4i >> 5, c4 = f4i & 31;
        *(float4*)&als[row][c4 * 4] =
            *(const float4*)&alpha[(size_t)(bn * 16 + row) * MM + bm * 128 + c4 * 4];
    }
    __syncthreads();

    float acc[4][4];
    #pragma unroll
    for (int n = 0; n < 4; ++n)
        #pragma unroll
        for (int j = 0; j < 4; ++j) acc[n][j] = 0.f;

    const float* fb = frp + (size_t)(bm * 128) * DD + 4 * dq;
    for (int m4 = 0; m4 < 32; ++m4) {
        float av[4][4];
        #pragma unroll
        for (int n = 0; n < 4; ++n) {
            float4 a4 = *(const float4*)&als[ng * 4 + n][m4 * 4];
            av[n][0] = a4.x; av[n][1] = a4.y; av[n][2] = a4.z; av[n][3] = a4.w;
        }
        #pragma unroll
        for (int mm = 0; mm < 4; ++mm) {
            float4 f4 = *(const float4*)(fb + (size_t)(m4 * 4 + mm) * DD);
            float fv[4] = {f4.x, f4.y, f4.z, f4.w};
            #pragma unroll
            for (int n = 0; n < 4; ++n)
                #pragma unroll
                for (int j = 0; j < 4; ++j)
                    acc[n][j] = fmaf(av[n][mm], fv[j], acc[n][j]);
        }
    }
    #pragma unroll
    for (int n = 0; n < 4; ++n)
        *(float4*)&part[((size_t)bm << 18) + (size_t)(bn * 16 + ng * 4 + n) * DD + 4 * dq] =
            make_float4(acc[n][0], acc[n][1], acc[n][2], acc[n][3]);
}

// ---------------- K2c: reduce m-split partials -> ctx, stage-2 raw scores ----------------
__global__ __launch_bounds__(256) void ctx_reduce_kernel(
    const float* __restrict__ part, const float* __restrict__ wp_w,
    float* __restrict__ ctx, float* __restrict__ score)
{
    __shared__ float red[4];
    const int t = threadIdx.x;
    const int n = blockIdx.x;
    const int lane = t & 63, wid = t >> 6;
    size_t idx = (size_t)n * DD + t;
    float c = 0.f;
    #pragma unroll
    for (int s = 0; s < 8; ++s) c += part[idx + ((size_t)s << 18)];
    ctx[idx] = c;
    float p = c * wp_w[t];
    #pragma unroll
    for (int off = 32; off > 0; off >>= 1) p += __shfl_xor(p, off);
    if (lane == 0) red[wid] = p;
    __syncthreads();
    if (t == 0) score[n] = red[0] + red[1] + red[2] + red[3];
}

// ---------------- K3: softmax over N + pooled sum ----------------
__global__ __launch_bounds__(256) void pool_kernel(
    const float* __restrict__ ctx, const float* __restrict__ score,
    float* __restrict__ out)
{
    __shared__ float red[8];
    __shared__ float wloc[16];
    const int t = threadIdx.x, lane = t & 63, wid = t >> 6;

    float s0 = score[t], s1 = score[t + 256], s2 = score[t + 512], s3 = score[t + 768];
    float mx = fmaxf(fmaxf(s0, s1), fmaxf(s2, s3));
    #pragma unroll
    for (int off = 32; off > 0; off >>= 1) mx = fmaxf(mx, __shfl_xor(mx, off));
    if (lane == 0) red[wid] = mx;
    __syncthreads();
    mx = fmaxf(fmaxf(red[0], red[1]), fmaxf(red[2], red[3]));

    float se = __expf(s0 - mx) + __expf(s1 - mx) + __expf(s2 - mx) + __expf(s3 - mx);
    #pragma unroll
    for (int off = 32; off > 0; off >>= 1) se += __shfl_xor(se, off);
    if (lane == 0) red[4 + wid] = se;
    __syncthreads();
    se = red[4] + red[5] + red[6] + red[7];
    float invS = rcp_fast(se);

    if (t < 16) wloc[t] = __expf(score[blockIdx.x * 16 + t] - mx) * invS;
    __syncthreads();

    float pool = 0.f;
    const float* cb = ctx + (size_t)(blockIdx.x * 16) * DD + t;
    #pragma unroll
    for (int i = 0; i < 16; ++i) pool = fmaf(wloc[i], cb[i * DD], pool);
    atomicAdd(out + t, pool);
}

extern "C" void kernel_launch(void* const* d_in, const int* in_sizes, int n_in,
                              void* d_out, int out_size, void* d_ws, size_t ws_size,
                              hipStream_t stream) {
    const float* f_r  = (const float*)d_in[0];
    const float* f_rp = (const float*)d_in[1];
    const float* W_w  = (const float*)d_in[2];
    const float* W_b  = (const float*)d_in[3];
    const float* Wp_w = (const float*)d_in[4];
    const float* Wp_b = (const float*)d_in[5];
    const float* w_w  = (const float*)d_in[6];
    // d_in[7] = w_b  : cancels in softmax over m
    const float* wp_w = (const float*)d_in[8];
    // d_in[9] = wp_b : cancels in softmax over n
    float* out = (float*)d_out;

    float* ws    = (float*)d_ws;
    float* Eq    = ws;                  // 256K floats
    float* EkT   = ws + 262144;         // 256K
    float* alpha = ws + 524288;         // 1M
    float* part  = ws + 1572864;        // 8 x 256K
    float* ctx   = ws + 3670016;        // 256K
    float* score = ws + 3932160;        // 1K

    gemm_exp_kernel<<<256, 256, 0, stream>>>(f_r, W_w, W_b, f_rp, Wp_w, Wp_b, Eq, EkT, out);
    score_softmax_kernel<<<512, 512, 0, stream>>>(Eq, EkT, w_w, alpha);
    context_kernel<<<512, 256, 0, stream>>>(alpha, f_rp, part);
    ctx_reduce_kernel<<<1024, 256, 0, stream>>>(part, wp_w, ctx, score);
    pool_kernel<<<64, 256, 0, stream>>>(ctx, score, out);
}